// Round 1
// baseline (513.865 us; speedup 1.0000x reference)
//
#include <hip/hip_runtime.h>
#include <hip/hip_bf16.h>

// ---------------------------------------------------------------------------
// Fused attention head: q = X@Wq+bq etc (f32 in), softmax(q k^T / sqrt(128)) v
// B=4, S=4096, D_IN=1024, D=128.  Compute in bf16 MFMA (16x16x32), f32 accum.
// Pipeline: prep_weights -> qkv_proj (writes Q,K row-major bf16; V transposed)
//           -> attn_fwd (flash, swapped-QK^T, s-split=2) -> merge_out
// ---------------------------------------------------------------------------

typedef __attribute__((ext_vector_type(8))) short v8s;   // 8 x bf16 (MFMA A/B frag)
typedef __attribute__((ext_vector_type(4))) float v4f;   // MFMA C/D frag
typedef __attribute__((ext_vector_type(2))) unsigned int v2u;

#define SEQ   4096
#define DIN   1024
#define DH    128
#define NBAT  4

// f32 -> bf16 round-to-nearest-even (matches numpy)
__device__ __forceinline__ unsigned short f2bf(float f) {
  unsigned u = __float_as_uint(f);
  u += 0x7fffu + ((u >> 16) & 1u);
  return (unsigned short)(u >> 16);
}

// --------------------------------------------------------------------------
// Kernel 0: Wt[z][c][k] = bf16(W_z[k][c]);  z in {q,k,v}.  [3][128][1024]
// --------------------------------------------------------------------------
__global__ void prep_weights(const float* __restrict__ Wq, const float* __restrict__ Wk,
                             const float* __restrict__ Wv, short* __restrict__ Wt) {
  int idx = blockIdx.x * 256 + threadIdx.x;          // 0 .. 3*131072-1
  int z = idx >> 17;
  int e = idx & 131071;                              // k*128 + c
  int k = e >> 7, c = e & 127;
  const float* W = (z == 0) ? Wq : (z == 1) ? Wk : Wv;
  Wt[z * 131072 + c * 1024 + k] = (short)f2bf(W[e]);
}

// --------------------------------------------------------------------------
// Kernel 1: projection GEMM  Out[16384,128] = X[16384,1024] @ W[1024,128] + b
// blockIdx.y = z (0:q row-major, 1:k row-major, 2:v transposed)
// 256 threads = 4 waves, BM=128, BK=32.  A converted f32->bf16 at staging.
// LDS layout [kc 0..3][row 0..127][8 bf16] => frag reads are contiguous 16B.
// --------------------------------------------------------------------------
__global__ __launch_bounds__(256) void qkv_proj(
    const float* __restrict__ Xq, const float* __restrict__ Xk, const float* __restrict__ Xv,
    const float* __restrict__ bq, const float* __restrict__ bk, const float* __restrict__ bv,
    const short* __restrict__ Wt,
    short* __restrict__ Qb, short* __restrict__ Kb, short* __restrict__ Vtb) {
  __shared__ __align__(16) short Asl[2][4][128][8];   // 16 KB
  __shared__ __align__(16) short Bsl[2][4][128][8];   // 16 KB

  const int z = blockIdx.y;
  const float* X    = (z == 0) ? Xq : (z == 1) ? Xk : Xv;
  const float* bias = (z == 0) ? bq : (z == 1) ? bk : bv;
  const short* W    = Wt + z * 131072;

  const int tid   = threadIdx.x;
  const int bm0   = blockIdx.x * 128;
  const int srow  = tid & 127;      // staging row (A) / col (B)
  const int khalf = tid >> 7;       // which 16-element k-half of the 32-k step

  const float* xp = X + (size_t)(bm0 + srow) * DIN + khalf * 16;
  const short* wp = W + srow * 1024 + khalf * 16;

  const int wid = tid >> 6, lane = tid & 63;
  const int wr = wid >> 1, wc = wid & 1;
  const int lg = lane >> 4, li = lane & 15;

  v4f acc[4][4];
#pragma unroll
  for (int mi = 0; mi < 4; ++mi)
#pragma unroll
    for (int ni = 0; ni < 4; ++ni) { acc[mi][ni][0]=0.f; acc[mi][ni][1]=0.f; acc[mi][ni][2]=0.f; acc[mi][ni][3]=0.f; }

  auto stage = [&](int buf, int ks) {
    const float* xs = xp + ks * 32;
    v4f x0 = *(const v4f*)(xs);
    v4f x1 = *(const v4f*)(xs + 4);
    v4f x2 = *(const v4f*)(xs + 8);
    v4f x3 = *(const v4f*)(xs + 12);
    const short* wsrc = wp + ks * 32;
    v8s w0 = *(const v8s*)(wsrc);
    v8s w1 = *(const v8s*)(wsrc + 8);
    v8s a0, a1;
    a0[0]=(short)f2bf(x0[0]); a0[1]=(short)f2bf(x0[1]); a0[2]=(short)f2bf(x0[2]); a0[3]=(short)f2bf(x0[3]);
    a0[4]=(short)f2bf(x1[0]); a0[5]=(short)f2bf(x1[1]); a0[6]=(short)f2bf(x1[2]); a0[7]=(short)f2bf(x1[3]);
    a1[0]=(short)f2bf(x2[0]); a1[1]=(short)f2bf(x2[1]); a1[2]=(short)f2bf(x2[2]); a1[3]=(short)f2bf(x2[3]);
    a1[4]=(short)f2bf(x3[0]); a1[5]=(short)f2bf(x3[1]); a1[6]=(short)f2bf(x3[2]); a1[7]=(short)f2bf(x3[3]);
    *(v8s*)&Asl[buf][khalf * 2 + 0][srow][0] = a0;
    *(v8s*)&Asl[buf][khalf * 2 + 1][srow][0] = a1;
    *(v8s*)&Bsl[buf][khalf * 2 + 0][srow][0] = w0;
    *(v8s*)&Bsl[buf][khalf * 2 + 1][srow][0] = w1;
  };

  stage(0, 0);
  __syncthreads();
#pragma unroll 1
  for (int ks = 0; ks < 32; ++ks) {
    const int cur = ks & 1;
    if (ks < 31) stage(cur ^ 1, ks + 1);
    v8s a[4], b[4];
#pragma unroll
    for (int mi = 0; mi < 4; ++mi) a[mi] = *(const v8s*)&Asl[cur][lg][wr * 64 + mi * 16 + li][0];
#pragma unroll
    for (int ni = 0; ni < 4; ++ni) b[ni] = *(const v8s*)&Bsl[cur][lg][wc * 64 + ni * 16 + li][0];
#pragma unroll
    for (int mi = 0; mi < 4; ++mi)
#pragma unroll
      for (int ni = 0; ni < 4; ++ni)
        acc[mi][ni] = __builtin_amdgcn_mfma_f32_16x16x32_bf16(a[mi], b[ni], acc[mi][ni], 0, 0, 0);
    __syncthreads();
  }

  // epilogue: C/D layout col = li (+16*ni +64*wc), rows = 4*lg + r (+16*mi +64*wr)
#pragma unroll
  for (int ni = 0; ni < 4; ++ni) {
    const int col = wc * 64 + ni * 16 + li;
    const float bb = bias[col];
#pragma unroll
    for (int mi = 0; mi < 4; ++mi) {
      const int row0 = bm0 + wr * 64 + mi * 16 + lg * 4;
      v4f r = acc[mi][ni];
      if (z < 2) {
        short* Out = (z == 0) ? Qb : Kb;
#pragma unroll
        for (int rr = 0; rr < 4; ++rr)
          Out[(size_t)(row0 + rr) * DH + col] = (short)f2bf(r[rr] + bb);
      } else {
        const int bat = row0 >> 12;
        const int s0  = row0 & 4095;
        unsigned lo = (unsigned)f2bf(r[0] + bb) | ((unsigned)f2bf(r[1] + bb) << 16);
        unsigned hi = (unsigned)f2bf(r[2] + bb) | ((unsigned)f2bf(r[3] + bb) << 16);
        v2u pk; pk[0] = lo; pk[1] = hi;
        *(v2u*)&Vtb[(size_t)bat * (DH * SEQ) + (size_t)col * SEQ + s0] = pk;  // Vt[b][d][s]
      }
    }
  }
}

// --------------------------------------------------------------------------
// Kernel 2: flash attention.  One wave = 16 query rows; 4 waves/block.
// Swapped QK^T: St = mfma(K_frag, Q_frag) => lane holds col q=li, rows s.
// Softmax per q: in-lane reduce over 16 vals + shfl_xor(16,32).
// P -> per-wave XOR-swizzled LDS -> A-frag for PV.  V read from Vt[d][s].
// NSPLIT: s-range split across blockIdx.z with unnormalized partials.
// --------------------------------------------------------------------------
template <int NSPLIT>
__global__ __launch_bounds__(256) void attn_fwd(
    const short* __restrict__ Qb, const short* __restrict__ Kb, const short* __restrict__ Vtb,
    float* __restrict__ out, float* __restrict__ Opart,
    float* __restrict__ Mpart, float* __restrict__ Lpart) {
  constexpr int SLEN = SEQ / NSPLIT;
  __shared__ __align__(16) char Pt[4][2048];   // per-wave 16x64 bf16 P tile (swizzled)

  const int tid = threadIdx.x, wid = tid >> 6, lane = tid & 63;
  const int lg = lane >> 4, li = lane & 15;
  const int b = blockIdx.y;
  const int q0 = blockIdx.x * 64 + wid * 16;
  const int sp = (NSPLIT > 1) ? blockIdx.z : 0;
  const float kSc = 0.08838834764831845f * 1.4426950408889634f;  // 1/sqrt(128) * log2(e)

  const short* Q  = Qb + ((size_t)b * SEQ + q0) * DH;
  const short* K  = Kb + ((size_t)b * SEQ + sp * SLEN) * DH;
  const short* Vt = Vtb + (size_t)b * (DH * SEQ) + sp * SLEN;
  char* myPt = Pt[wid];

  // hoist Q fragments (B-operand of swapped QK^T): lane reads Q[q=li][dc*32 + lg*8 ..]
  v8s qf[4];
#pragma unroll
  for (int dc = 0; dc < 4; ++dc) qf[dc] = *(const v8s*)&Q[li * DH + dc * 32 + lg * 8];

  v4f o[8];
#pragma unroll
  for (int dt = 0; dt < 8; ++dt) { o[dt][0]=0.f; o[dt][1]=0.f; o[dt][2]=0.f; o[dt][3]=0.f; }
  float m = -1e30f, l = 0.f;

#pragma unroll 1
  for (int st0 = 0; st0 < SLEN; st0 += 64) {
    const short* Kt = K + (size_t)st0 * DH;
    // ---- S^T = K @ Q^T : 4 s-tiles of 16, k = d (128 = 4 chunks of 32)
    v4f stt[4];
#pragma unroll
    for (int t = 0; t < 4; ++t) { stt[t][0]=0.f; stt[t][1]=0.f; stt[t][2]=0.f; stt[t][3]=0.f; }
#pragma unroll
    for (int t = 0; t < 4; ++t)
#pragma unroll
      for (int dc = 0; dc < 4; ++dc) {
        v8s kf = *(const v8s*)&Kt[(size_t)(t * 16 + li) * DH + dc * 32 + lg * 8];
        stt[t] = __builtin_amdgcn_mfma_f32_16x16x32_bf16(kf, qf[dc], stt[t], 0, 0, 0);
      }
    // ---- online softmax over s for this lane's q=li (raw logits * kSc inside exp2)
    float mx = m;
#pragma unroll
    for (int t = 0; t < 4; ++t) {
      mx = fmaxf(mx, fmaxf(fmaxf(stt[t][0], stt[t][1]), fmaxf(stt[t][2], stt[t][3])));
    }
    mx = fmaxf(mx, __shfl_xor(mx, 16));
    mx = fmaxf(mx, __shfl_xor(mx, 32));
    const float fac = exp2f((m - mx) * kSc);
    m = mx;
    float ps = 0.f;
#pragma unroll
    for (int t = 0; t < 4; ++t) {
      float p0 = exp2f((stt[t][0] - mx) * kSc);
      float p1 = exp2f((stt[t][1] - mx) * kSc);
      float p2 = exp2f((stt[t][2] - mx) * kSc);
      float p3 = exp2f((stt[t][3] - mx) * kSc);
      ps += (p0 + p1) + (p2 + p3);
      unsigned lo = (unsigned)f2bf(p0) | ((unsigned)f2bf(p1) << 16);
      unsigned hi = (unsigned)f2bf(p2) | ((unsigned)f2bf(p3) << 16);
      v2u pk; pk[0] = lo; pk[1] = hi;
      int off = (li * 128 + t * 32 + lg * 8) ^ ((li & 7) << 4);   // swizzled write
      *(v2u*)(myPt + off) = pk;
    }
    ps += __shfl_xor(ps, 16);
    ps += __shfl_xor(ps, 32);
    l = l * fac + ps;
    // redistribute rescale factor to O's row layout (row q = 4*lg + r)
    float facr[4];
#pragma unroll
    for (int r = 0; r < 4; ++r) facr[r] = __shfl(fac, lg * 4 + r);
#pragma unroll
    for (int dt = 0; dt < 8; ++dt) {
      o[dt][0] *= facr[0]; o[dt][1] *= facr[1]; o[dt][2] *= facr[2]; o[dt][3] *= facr[3];
    }
    // ---- PV: O[q][d] += P[q][s] * V[s][d];  A-frag from swizzled LDS, B from Vt
#pragma unroll
    for (int kk = 0; kk < 2; ++kk) {
      v8s pf = *(const v8s*)(myPt + ((li * 128 + kk * 64 + lg * 16) ^ ((li & 7) << 4)));
#pragma unroll
      for (int dt = 0; dt < 8; ++dt) {
        v8s vf = *(const v8s*)&Vt[(size_t)(dt * 16 + li) * SEQ + st0 + kk * 32 + lg * 8];
        o[dt] = __builtin_amdgcn_mfma_f32_16x16x32_bf16(pf, vf, o[dt], 0, 0, 0);
      }
    }
  }

  // ---- epilogue
  float lr[4];
#pragma unroll
  for (int r = 0; r < 4; ++r) lr[r] = __shfl(l, lg * 4 + r);
  if (NSPLIT == 1) {
    float inv[4];
#pragma unroll
    for (int r = 0; r < 4; ++r) inv[r] = 1.f / lr[r];
#pragma unroll
    for (int dt = 0; dt < 8; ++dt)
#pragma unroll
      for (int r = 0; r < 4; ++r)
        out[((size_t)b * SEQ + q0 + lg * 4 + r) * DH + dt * 16 + li] = o[dt][r] * inv[r];
  } else {
    const size_t rb = (size_t)sp * (NBAT * SEQ) + (size_t)b * SEQ + q0;
#pragma unroll
    for (int dt = 0; dt < 8; ++dt)
#pragma unroll
      for (int r = 0; r < 4; ++r)
        Opart[(rb + lg * 4 + r) * DH + dt * 16 + li] = o[dt][r];
    if (lg == 0) { Mpart[rb + li] = m; Lpart[rb + li] = l; }
  }
}

// --------------------------------------------------------------------------
// Kernel 3: merge the s-split partials.
// --------------------------------------------------------------------------
template <int NSPLIT>
__global__ void merge_out(const float* __restrict__ Opart, const float* __restrict__ Mpart,
                          const float* __restrict__ Lpart, float* __restrict__ out) {
  const float kSc = 0.08838834764831845f * 1.4426950408889634f;
  int idx = blockIdx.x * 256 + threadIdx.x;     // 0 .. 2097151
  int row = idx >> 7;
  float M = -1e30f;
#pragma unroll
  for (int zz = 0; zz < NSPLIT; ++zz) M = fmaxf(M, Mpart[zz * (NBAT * SEQ) + row]);
  float num = 0.f, den = 0.f;
#pragma unroll
  for (int zz = 0; zz < NSPLIT; ++zz) {
    float w = exp2f((Mpart[zz * (NBAT * SEQ) + row] - M) * kSc);
    num += w * Opart[(size_t)zz * (NBAT * SEQ * DH) + idx];
    den += w * Lpart[zz * (NBAT * SEQ) + row];
  }
  out[idx] = num / den;
}

// --------------------------------------------------------------------------
extern "C" void kernel_launch(void* const* d_in, const int* in_sizes, int n_in,
                              void* d_out, int out_size, void* d_ws, size_t ws_size,
                              hipStream_t stream) {
  const float* query = (const float*)d_in[0];
  const float* key   = (const float*)d_in[1];
  const float* value = (const float*)d_in[2];
  const float* Wq    = (const float*)d_in[3];
  const float* bqp   = (const float*)d_in[4];
  const float* Wk    = (const float*)d_in[5];
  const float* bkp   = (const float*)d_in[6];
  const float* Wv    = (const float*)d_in[7];
  const float* bvp   = (const float*)d_in[8];

  char* ws = (char*)d_ws;
  const size_t WT_SZ  = (size_t)3 * 128 * 1024 * 2;       //   786432
  const size_t QKV_SZ = (size_t)NBAT * SEQ * DH * 2;      //  4194304
  short* Wt  = (short*)ws;
  short* Qb  = (short*)(ws + WT_SZ);
  short* Kb  = (short*)(ws + WT_SZ + QKV_SZ);
  short* Vtb = (short*)(ws + WT_SZ + 2 * QKV_SZ);
  char*  ext = ws + WT_SZ + 3 * QKV_SZ;                   // 13369344
  const size_t OPART_SZ = (size_t)2 * NBAT * SEQ * DH * 4;   // 16777216
  const size_t STAT_SZ  = (size_t)2 * NBAT * SEQ * 4;        //   131072
  float* Opart = (float*)ext;
  float* Mpart = (float*)(ext + OPART_SZ);
  float* Lpart = (float*)(ext + OPART_SZ + STAT_SZ);
  const bool split = ws_size >= (WT_SZ + 3 * QKV_SZ + OPART_SZ + 2 * STAT_SZ);

  prep_weights<<<1536, 256, 0, stream>>>(Wq, Wk, Wv, Wt);
  qkv_proj<<<dim3(128, 3), 256, 0, stream>>>(query, key, value, bqp, bkp, bvp,
                                             Wt, Qb, Kb, Vtb);
  if (split) {
    attn_fwd<2><<<dim3(64, NBAT, 2), 256, 0, stream>>>(Qb, Kb, Vtb, nullptr, Opart, Mpart, Lpart);
    merge_out<2><<<8192, 256, 0, stream>>>(Opart, Mpart, Lpart, (float*)d_out);
  } else {
    attn_fwd<1><<<dim3(64, NBAT, 1), 256, 0, stream>>>(Qb, Kb, Vtb, (float*)d_out,
                                                       nullptr, nullptr, nullptr);
  }
}

// Round 5
// 393.115 us; speedup vs baseline: 1.3072x; 1.3072x over previous
//
#include <hip/hip_runtime.h>
#include <hip/hip_bf16.h>

// ---------------------------------------------------------------------------
// Fused attention head. B=4, S=4096, D_IN=1024, D=128. bf16 MFMA 16x16x32.
// prep_weights -> qkv_proj (no-LDS streaming GEMM; V written transposed)
//   -> attn_fwd (flash, swapped QK^T, LDS-staged K/V dbuf, s-split) -> merge
// ---------------------------------------------------------------------------

typedef __attribute__((ext_vector_type(8))) short v8s;   // 8 x bf16
typedef __attribute__((ext_vector_type(4))) float v4f;   // MFMA C/D frag
typedef __attribute__((ext_vector_type(2))) unsigned int v2u;
typedef __attribute__((ext_vector_type(4))) int v4i;     // 16B staging chunk

#define SEQ   4096
#define DIN   1024
#define DH    128
#define NBAT  4

// f32 -> bf16 round-to-nearest-even
__device__ __forceinline__ unsigned short f2bf(float f) {
  unsigned u = __float_as_uint(f);
  u += 0x7fffu + ((u >> 16) & 1u);
  return (unsigned short)(u >> 16);
}

// --------------------------------------------------------------------------
// Kernel 0: Wt[z][c][k] = bf16(W_z[k][c]);  [3][128][1024]
// --------------------------------------------------------------------------
__global__ void prep_weights(const float* __restrict__ Wq, const float* __restrict__ Wk,
                             const float* __restrict__ Wv, short* __restrict__ Wt) {
  int idx = blockIdx.x * 256 + threadIdx.x;
  int z = idx >> 17;
  int e = idx & 131071;                              // k*128 + c
  int k = e >> 7, c = e & 127;
  const float* W = (z == 0) ? Wq : (z == 1) ? Wk : Wv;
  Wt[z * 131072 + c * 1024 + k] = (short)f2bf(W[e]);
}

// --------------------------------------------------------------------------
// Kernel 1: Out[16384,128] = X[16384,1024] @ W + b.  blockIdx.y = z.
// No LDS, no barriers: wave = 32 rows x 128 cols; X f32 direct (cvt in reg),
// W B-frags direct from L2-resident Wt[c][k].  Grid (128,3) = 1536 waves.
// --------------------------------------------------------------------------
__global__ __launch_bounds__(256) void qkv_proj(
    const float* __restrict__ Xq, const float* __restrict__ Xk, const float* __restrict__ Xv,
    const float* __restrict__ bq, const float* __restrict__ bk, const float* __restrict__ bv,
    const short* __restrict__ Wt,
    short* __restrict__ Qb, short* __restrict__ Kb, short* __restrict__ Vtb) {
  const int z = blockIdx.y;
  const float* X    = (z == 0) ? Xq : (z == 1) ? Xk : Xv;
  const float* bias = (z == 0) ? bq : (z == 1) ? bk : bv;
  const short* W    = Wt + z * 131072;

  const int tid = threadIdx.x, wid = tid >> 6, lane = tid & 63;
  const int lg = lane >> 4, li = lane & 15;
  const int r0 = blockIdx.x * 128 + wid * 32;

  const float* xp0 = X + (size_t)(r0 + li) * DIN + lg * 8;
  const float* xp1 = xp0 + (size_t)16 * DIN;

  v4f acc[2][8];
#pragma unroll
  for (int mi = 0; mi < 2; ++mi)
#pragma unroll
    for (int ni = 0; ni < 8; ++ni) { acc[mi][ni][0]=0.f; acc[mi][ni][1]=0.f; acc[mi][ni][2]=0.f; acc[mi][ni][3]=0.f; }

#pragma unroll 2
  for (int ks = 0; ks < 32; ++ks) {
    v4f x0 = *(const v4f*)(xp0 + ks * 32);
    v4f x1 = *(const v4f*)(xp0 + ks * 32 + 4);
    v4f y0 = *(const v4f*)(xp1 + ks * 32);
    v4f y1 = *(const v4f*)(xp1 + ks * 32 + 4);
    v8s a0, a1;
    a0[0]=(short)f2bf(x0[0]); a0[1]=(short)f2bf(x0[1]); a0[2]=(short)f2bf(x0[2]); a0[3]=(short)f2bf(x0[3]);
    a0[4]=(short)f2bf(x1[0]); a0[5]=(short)f2bf(x1[1]); a0[6]=(short)f2bf(x1[2]); a0[7]=(short)f2bf(x1[3]);
    a1[0]=(short)f2bf(y0[0]); a1[1]=(short)f2bf(y0[1]); a1[2]=(short)f2bf(y0[2]); a1[3]=(short)f2bf(y0[3]);
    a1[4]=(short)f2bf(y1[0]); a1[5]=(short)f2bf(y1[1]); a1[6]=(short)f2bf(y1[2]); a1[7]=(short)f2bf(y1[3]);
#pragma unroll
    for (int ni = 0; ni < 8; ++ni) {
      v8s b = *(const v8s*)&W[(ni * 16 + li) * DIN + ks * 32 + lg * 8];
      acc[0][ni] = __builtin_amdgcn_mfma_f32_16x16x32_bf16(a0, b, acc[0][ni], 0, 0, 0);
      acc[1][ni] = __builtin_amdgcn_mfma_f32_16x16x32_bf16(a1, b, acc[1][ni], 0, 0, 0);
    }
  }

  // epilogue: C/D col = ni*16+li, rows = r0 + mi*16 + lg*4 + r
#pragma unroll
  for (int ni = 0; ni < 8; ++ni) {
    const int col = ni * 16 + li;
    const float bb = bias[col];
#pragma unroll
    for (int mi = 0; mi < 2; ++mi) {
      const int row0 = r0 + mi * 16 + lg * 4;
      v4f r = acc[mi][ni];
      if (z < 2) {
        short* Out = (z == 0) ? Qb : Kb;
#pragma unroll
        for (int rr = 0; rr < 4; ++rr)
          Out[(size_t)(row0 + rr) * DH + col] = (short)f2bf(r[rr] + bb);
      } else {
        const int bat = row0 >> 12;
        const int s0  = row0 & 4095;
        unsigned lo = (unsigned)f2bf(r[0] + bb) | ((unsigned)f2bf(r[1] + bb) << 16);
        unsigned hi = (unsigned)f2bf(r[2] + bb) | ((unsigned)f2bf(r[3] + bb) << 16);
        v2u pk; pk[0] = lo; pk[1] = hi;
        *(v2u*)&Vtb[(size_t)bat * (DH * SEQ) + (size_t)col * SEQ + s0] = pk;  // Vt[b][d][s]
      }
    }
  }
}

// --------------------------------------------------------------------------
// Kernel 2: flash attention.  4 waves/block, QBLK=32/wave (block = 128 q).
// K tile [64][128] and Vt tile [128][64] in LDS, XOR-swizzled ^((row&7)<<4),
// double-buffered via reg-staging (loads issued before compute, ds_write
// after: T14).  Swapped QK^T; P via per-wave swizzled LDS tile.
// --------------------------------------------------------------------------
template <int NSPLIT>
__global__ __launch_bounds__(256) void attn_fwd(
    const short* __restrict__ Qb, const short* __restrict__ Kb, const short* __restrict__ Vtb,
    float* __restrict__ out, float* __restrict__ Opart,
    float* __restrict__ Mpart, float* __restrict__ Lpart) {
  constexpr int SLEN = SEQ / NSPLIT;
  constexpr int NT = SLEN / 64;
  __shared__ __align__(16) short Kl[2][64 * 128];   // 32 KB
  __shared__ __align__(16) short Vl[2][128 * 64];   // 32 KB
  __shared__ __align__(16) short Pl[4][32 * 64];    // 16 KB (per-wave 4 KB)

  const int tid = threadIdx.x, wid = tid >> 6, lane = tid & 63;
  const int lg = lane >> 4, li = lane & 15;
  const int b = blockIdx.y;
  const int sp = (NSPLIT > 1) ? blockIdx.z : 0;
  const int q0 = blockIdx.x * 128 + wid * 32;
  const float kSc = 0.08838834764831845f * 1.4426950408889634f;  // 1/sqrt(128)*log2(e)
  const int swz = (li & 7) << 4;

  const char* Kp = (const char*)(Kb + ((size_t)b * SEQ + (size_t)sp * SLEN) * DH);
  const char* Vp = (const char*)(Vtb + (size_t)b * (DH * SEQ) + (size_t)sp * SLEN);
  const short* Q = Qb + ((size_t)b * SEQ + q0) * DH;
  char* myP = (char*)&Pl[wid][0];

  // hoist Q frags: qf[dc][qh] = Q[qh*16+li][dc*32 + lg*8 ..]
  v8s qf[4][2];
#pragma unroll
  for (int dc = 0; dc < 4; ++dc)
#pragma unroll
    for (int qh = 0; qh < 2; ++qh)
      qf[dc][qh] = *(const v8s*)&Q[(size_t)(qh * 16 + li) * DH + dc * 32 + lg * 8];

  v4f o[8][2];
#pragma unroll
  for (int dt = 0; dt < 8; ++dt)
#pragma unroll
    for (int qh = 0; qh < 2; ++qh) { o[dt][qh][0]=0.f; o[dt][qh][1]=0.f; o[dt][qh][2]=0.f; o[dt][qh][3]=0.f; }
  float m[2] = {-1e30f, -1e30f}, l[2] = {0.f, 0.f};

  v4i kreg[4], vreg[4];
  auto loadKV = [&](int st0) {
#pragma unroll
    for (int j = 0; j < 4; ++j) {
      int c = tid + j * 256;
      kreg[j] = *(const v4i*)(Kp + (size_t)st0 * 256 + c * 16);
    }
#pragma unroll
    for (int j = 0; j < 4; ++j) {
      int c = tid + j * 256;
      int d = c >> 3;
      vreg[j] = *(const v4i*)(Vp + (size_t)d * (SEQ * 2) + st0 * 2 + (c & 7) * 16);
    }
  };
  auto writeKV = [&](int buf) {
    char* kb = (char*)&Kl[buf][0];
    char* vb = (char*)&Vl[buf][0];
#pragma unroll
    for (int j = 0; j < 4; ++j) {
      int lin = (tid + j * 256) * 16;
      *(v4i*)(kb + (lin ^ (((lin >> 8) & 7) << 4))) = kreg[j];
    }
#pragma unroll
    for (int j = 0; j < 4; ++j) {
      int lin = (tid + j * 256) * 16;
      *(v4i*)(vb + (lin ^ (((lin >> 7) & 7) << 4))) = vreg[j];
    }
  };

  loadKV(0);
  writeKV(0);

#pragma unroll 1
  for (int t = 0; t < NT; ++t) {
    __syncthreads();                      // staged tile t visible
    const int buf = t & 1;
    if (t + 1 < NT) loadKV((t + 1) * 64); // issue next-tile loads (land during compute)
    const char* kb = (const char*)&Kl[buf][0];
    const char* vb = (const char*)&Vl[buf][0];

    // ---- S^T = K @ Q^T
    v4f stt[4][2];
#pragma unroll
    for (int tt = 0; tt < 4; ++tt)
#pragma unroll
      for (int qh = 0; qh < 2; ++qh) { stt[tt][qh][0]=0.f; stt[tt][qh][1]=0.f; stt[tt][qh][2]=0.f; stt[tt][qh][3]=0.f; }
#pragma unroll
    for (int tt = 0; tt < 4; ++tt)
#pragma unroll
      for (int dc = 0; dc < 4; ++dc) {
        v8s kf = *(const v8s*)(kb + ((((tt * 16 + li) * 256) + dc * 64 + lg * 16) ^ swz));
        stt[tt][0] = __builtin_amdgcn_mfma_f32_16x16x32_bf16(kf, qf[dc][0], stt[tt][0], 0, 0, 0);
        stt[tt][1] = __builtin_amdgcn_mfma_f32_16x16x32_bf16(kf, qf[dc][1], stt[tt][1], 0, 0, 0);
      }

    // ---- online softmax (lane owns q = qh*16 + li; s spread over regs+lg)
    float fac[2];
#pragma unroll
    for (int qh = 0; qh < 2; ++qh) {
      float mx = m[qh];
#pragma unroll
      for (int tt = 0; tt < 4; ++tt)
        mx = fmaxf(mx, fmaxf(fmaxf(stt[tt][qh][0], stt[tt][qh][1]), fmaxf(stt[tt][qh][2], stt[tt][qh][3])));
      mx = fmaxf(mx, __shfl_xor(mx, 16));
      mx = fmaxf(mx, __shfl_xor(mx, 32));
      fac[qh] = exp2f((m[qh] - mx) * kSc);
      m[qh] = mx;
      float ps = 0.f;
#pragma unroll
      for (int tt = 0; tt < 4; ++tt) {
        float p0 = exp2f((stt[tt][qh][0] - mx) * kSc);
        float p1 = exp2f((stt[tt][qh][1] - mx) * kSc);
        float p2 = exp2f((stt[tt][qh][2] - mx) * kSc);
        float p3 = exp2f((stt[tt][qh][3] - mx) * kSc);
        ps += (p0 + p1) + (p2 + p3);
        v2u pk;
        pk[0] = (unsigned)f2bf(p0) | ((unsigned)f2bf(p1) << 16);
        pk[1] = (unsigned)f2bf(p2) | ((unsigned)f2bf(p3) << 16);
        *(v2u*)(myP + ((((qh * 16 + li) * 128) + tt * 32 + lg * 8) ^ swz)) = pk;
      }
      ps += __shfl_xor(ps, 16);
      ps += __shfl_xor(ps, 32);
      l[qh] = l[qh] * fac[qh] + ps;
    }

    // ---- rescale O (row q = qh*16 + lg*4 + r)
    float facr[2][4];
#pragma unroll
    for (int qh = 0; qh < 2; ++qh)
#pragma unroll
      for (int r = 0; r < 4; ++r) facr[qh][r] = __shfl(fac[qh], lg * 4 + r);
#pragma unroll
    for (int dt = 0; dt < 8; ++dt)
#pragma unroll
      for (int qh = 0; qh < 2; ++qh) {
        o[dt][qh][0] *= facr[qh][0]; o[dt][qh][1] *= facr[qh][1];
        o[dt][qh][2] *= facr[qh][2]; o[dt][qh][3] *= facr[qh][3];
      }

    // ---- PV: O[q][d] += P[q][s] V[s][d]
#pragma unroll
    for (int kk = 0; kk < 2; ++kk) {
      v8s pf0 = *(const v8s*)(myP + (((li * 128) + kk * 64 + lg * 16) ^ swz));
      v8s pf1 = *(const v8s*)(myP + ((((16 + li) * 128) + kk * 64 + lg * 16) ^ swz));
#pragma unroll
      for (int dt = 0; dt < 8; ++dt) {
        v8s vf = *(const v8s*)(vb + ((((dt * 16 + li) * 128) + kk * 64 + lg * 16) ^ swz));
        o[dt][0] = __builtin_amdgcn_mfma_f32_16x16x32_bf16(pf0, vf, o[dt][0], 0, 0, 0);
        o[dt][1] = __builtin_amdgcn_mfma_f32_16x16x32_bf16(pf1, vf, o[dt][1], 0, 0, 0);
      }
    }

    if (t + 1 < NT) writeKV(buf ^ 1);     // swizzled ds_write into other buffer
  }

  // ---- epilogue
  float lr[2][4];
#pragma unroll
  for (int qh = 0; qh < 2; ++qh)
#pragma unroll
    for (int r = 0; r < 4; ++r) lr[qh][r] = __shfl(l[qh], lg * 4 + r);

  if (NSPLIT == 1) {
#pragma unroll
    for (int dt = 0; dt < 8; ++dt)
#pragma unroll
      for (int qh = 0; qh < 2; ++qh)
#pragma unroll
        for (int r = 0; r < 4; ++r)
          out[((size_t)b * SEQ + q0 + qh * 16 + lg * 4 + r) * DH + dt * 16 + li] =
              o[dt][qh][r] / lr[qh][r];
  } else {
    const size_t rb = ((size_t)sp * NBAT + b) * SEQ + q0;
#pragma unroll
    for (int dt = 0; dt < 8; ++dt)
#pragma unroll
      for (int qh = 0; qh < 2; ++qh)
#pragma unroll
        for (int r = 0; r < 4; ++r)
          Opart[(rb + qh * 16 + lg * 4 + r) * DH + dt * 16 + li] = o[dt][qh][r];
    if (lg == 0) {
#pragma unroll
      for (int qh = 0; qh < 2; ++qh) {
        Mpart[rb + qh * 16 + li] = m[qh];
        Lpart[rb + qh * 16 + li] = l[qh];
      }
    }
  }
}

// --------------------------------------------------------------------------
// Kernel 3: merge the s-split partials.
// --------------------------------------------------------------------------
template <int NSPLIT>
__global__ void merge_out(const float* __restrict__ Opart, const float* __restrict__ Mpart,
                          const float* __restrict__ Lpart, float* __restrict__ out) {
  const float kSc = 0.08838834764831845f * 1.4426950408889634f;
  int idx = blockIdx.x * 256 + threadIdx.x;     // 0 .. 2097151
  int row = idx >> 7;
  float M = -1e30f;
#pragma unroll
  for (int zz = 0; zz < NSPLIT; ++zz) M = fmaxf(M, Mpart[zz * (NBAT * SEQ) + row]);
  float num = 0.f, den = 0.f;
#pragma unroll
  for (int zz = 0; zz < NSPLIT; ++zz) {
    float w = exp2f((Mpart[zz * (NBAT * SEQ) + row] - M) * kSc);
    num += w * Opart[(size_t)zz * ((size_t)NBAT * SEQ * DH) + idx];
    den += w * Lpart[zz * (NBAT * SEQ) + row];
  }
  out[idx] = num / den;
}

// --------------------------------------------------------------------------
extern "C" void kernel_launch(void* const* d_in, const int* in_sizes, int n_in,
                              void* d_out, int out_size, void* d_ws, size_t ws_size,
                              hipStream_t stream) {
  const float* query = (const float*)d_in[0];
  const float* key   = (const float*)d_in[1];
  const float* value = (const float*)d_in[2];
  const float* Wq    = (const float*)d_in[3];
  const float* bqp   = (const float*)d_in[4];
  const float* Wk    = (const float*)d_in[5];
  const float* bkp   = (const float*)d_in[6];
  const float* Wv    = (const float*)d_in[7];
  const float* bvp   = (const float*)d_in[8];

  char* ws = (char*)d_ws;
  const size_t WT_SZ  = (size_t)3 * 128 * 1024 * 2;       //   786432
  const size_t QKV_SZ = (size_t)NBAT * SEQ * DH * 2;      //  4194304
  short* Wt  = (short*)ws;
  short* Qb  = (short*)(ws + WT_SZ);
  short* Kb  = (short*)(ws + WT_SZ + QKV_SZ);
  short* Vtb = (short*)(ws + WT_SZ + 2 * QKV_SZ);
  char*  ext = ws + WT_SZ + 3 * QKV_SZ;                   // 13369344
  const size_t OP4 = (size_t)4 * NBAT * SEQ * DH * 4;     // 33554432
  const size_t ST4 = (size_t)4 * NBAT * SEQ * 4;          //   262144
  const size_t OP2 = OP4 / 2, ST2 = ST4 / 2;
  const size_t need4 = WT_SZ + 3 * QKV_SZ + OP4 + 2 * ST4;
  const size_t need2 = WT_SZ + 3 * QKV_SZ + OP2 + 2 * ST2;

  prep_weights<<<1536, 256, 0, stream>>>(Wq, Wk, Wv, Wt);
  qkv_proj<<<dim3(128, 3), 256, 0, stream>>>(query, key, value, bqp, bkp, bvp,
                                             Wt, Qb, Kb, Vtb);
  if (ws_size >= need4) {
    float* Opart = (float*)ext;
    float* Mpart = (float*)(ext + OP4);
    float* Lpart = (float*)(ext + OP4 + ST4);
    attn_fwd<4><<<dim3(32, NBAT, 4), 256, 0, stream>>>(Qb, Kb, Vtb, nullptr, Opart, Mpart, Lpart);
    merge_out<4><<<8192, 256, 0, stream>>>(Opart, Mpart, Lpart, (float*)d_out);
  } else if (ws_size >= need2) {
    float* Opart = (float*)ext;
    float* Mpart = (float*)(ext + OP2);
    float* Lpart = (float*)(ext + OP2 + ST2);
    attn_fwd<2><<<dim3(32, NBAT, 2), 256, 0, stream>>>(Qb, Kb, Vtb, nullptr, Opart, Mpart, Lpart);
    merge_out<2><<<8192, 256, 0, stream>>>(Opart, Mpart, Lpart, (float*)d_out);
  } else {
    attn_fwd<1><<<dim3(32, NBAT, 1), 256, 0, stream>>>(Qb, Kb, Vtb, (float*)d_out,
                                                       nullptr, nullptr, nullptr);
  }
}